// Round 5
// baseline (119.649 us; speedup 1.0000x reference)
//
#include <hip/hip_runtime.h>
#include <math.h>

// x: (C,H,W) = (256,512,512) f32.  out = 2 * suffmax_W( suffmax_H( x ) )
// Key identity: suffmax_W and suffmax_H commute (both are max over the
// rows>=h, cols>=w quadrant). We scan W FIRST (carry-independent), so the
// post-barrier carry merge is purely elementwise.
constexpr int C     = 256;
constexpr int H     = 512;
constexpr int W     = 512;
constexpr int RPW   = 8;            // rows per wave per batch
constexpr int BATCH = 8 * RPW;      // 64 rows per batch -> 8 barriers total

__device__ __forceinline__ float4 fmax4(float4 x, float4 y) {
    return make_float4(fmaxf(x.x, y.x), fmaxf(x.y, y.y),
                       fmaxf(x.z, y.z), fmaxf(x.w, y.w));
}

// One 512-thread block per channel; each lane owns 8 consecutive columns so a
// 512-col W suffix-scan is one wave (7 in-lane fmax + 7 shuffles). Each wave
// owns 8 rows of a 64-row batch. Per batch:
//   1. issue next batch's 16 b128 loads (retire under this batch's work)
//   2. per-row W suffix scan IN PLACE (carry-independent heavy work)
//   3. in-wave H suffix chain over the 8 scanned rows (cheap fmax4)
//   4. publish wave totals, ONE barrier
//   5. elementwise carry merge (LDS b128 broadcasts) + coalesced store
__global__ __launch_bounds__(512)
void tlc_kernel(const float* __restrict__ x, float* __restrict__ out) {
    const int tid  = threadIdx.x;
    const int g    = tid >> 6;        // wave 0..7
    const int lane = tid & 63;
    const int c    = blockIdx.x;
    const int col  = lane * 8;        // first of this lane's 8 columns

    // double-buffered wave totals + running colmax (16B/lane contiguous
    // -> conflict-free b128). 36 KB total.
    __shared__ float4 ltotA[2][8][64], ltotB[2][8][64];
    __shared__ float4 gcolA[2][64],    gcolB[2][64];

    const float* __restrict__ xc = x   + (size_t)c * H * W;
    float*       __restrict__ oc = out + (size_t)c * H * W;

    // clamped source lanes for the suffix butterfly (loop-invariant)
    const int s1  = min(lane + 1, 63),  s2  = min(lane + 2, 63);
    const int s4  = min(lane + 4, 63),  s8  = min(lane + 8, 63);
    const int s16 = min(lane + 16, 63), s32 = min(lane + 32, 63);

    if (g == 0) {
        const float4 ninf = make_float4(-INFINITY, -INFINITY, -INFINITY, -INFINITY);
        gcolA[0][lane] = ninf;   // ordered before first read by batch-0 barrier
        gcolB[0][lane] = ninf;
    }

    int buf = 0;
    int rowbase = (H - BATCH) + RPW * g;   // this wave's first row of batch
    float4 cA[RPW], cB[RPW], nA[RPW], nB[RPW];

    #pragma unroll
    for (int r = 0; r < RPW; ++r) {
        const float* p = xc + (size_t)(rowbase + r) * W + col;
        cA[r] = *(const float4*)p;
        cB[r] = *(const float4*)(p + 4);
    }

    for (int hb = H - BATCH; hb >= 0; hb -= BATCH, rowbase -= BATCH) {
        // 1. next batch's loads — in flight across this entire batch
        if (hb >= BATCH) {
            #pragma unroll
            for (int r = 0; r < RPW; ++r) {
                const float* p = xc + (size_t)(rowbase - BATCH + r) * W + col;
                nA[r] = *(const float4*)p;
                nB[r] = *(const float4*)(p + 4);
            }
        }

        // 2. per-row W suffix scan, in place (no carry dependency)
        #pragma unroll
        for (int r = 0; r < RPW; ++r) {
            const float4 a = cA[r], b = cB[r];
            const float t7 = b.w;
            const float t6 = fmaxf(b.z, t7);
            const float t5 = fmaxf(b.y, t6);
            const float t4 = fmaxf(b.x, t5);
            const float t3 = fmaxf(a.w, t4);
            const float t2 = fmaxf(a.z, t3);
            const float t1 = fmaxf(a.y, t2);
            const float t0 = fmaxf(a.x, t1);

            // exclusive suffix of lane totals: shift-by-1 then clamped
            // inclusive butterfly (max over lanes > mine)
            float e = __shfl(t0, s1);
            e = (lane == 63) ? -INFINITY : e;
            e = fmaxf(e, __shfl(e, s1));
            e = fmaxf(e, __shfl(e, s2));
            e = fmaxf(e, __shfl(e, s4));
            e = fmaxf(e, __shfl(e, s8));
            e = fmaxf(e, __shfl(e, s16));
            e = fmaxf(e, __shfl(e, s32));

            cA[r] = make_float4(fmaxf(t0, e), fmaxf(t1, e),
                                fmaxf(t2, e), fmaxf(t3, e));
            cB[r] = make_float4(fmaxf(t4, e), fmaxf(t5, e),
                                fmaxf(t6, e), fmaxf(t7, e));
        }

        // 3. in-wave H suffix chain over the scanned rows (row r gets
        //    max of rows r..RPW-1)
        #pragma unroll
        for (int r = RPW - 2; r >= 0; --r) {
            cA[r] = fmax4(cA[r], cA[r + 1]);
            cB[r] = fmax4(cB[r], cB[r + 1]);
        }

        // 4. publish wave totals (row 0 = whole-wave column max)
        ltotA[buf][g][lane] = cA[0];
        ltotB[buf][g][lane] = cB[0];
        __syncthreads();   // the only barrier per 64 rows

        // 5. carry = max(running colmax, totals of waves below), elementwise
        float4 mA = gcolA[buf][lane];
        float4 mB = gcolB[buf][lane];
        for (int gg = g + 1; gg < 8; ++gg) {   // wave-uniform trip count
            mA = fmax4(mA, ltotA[buf][gg][lane]);
            mB = fmax4(mB, ltotB[buf][gg][lane]);
        }

        // wave 0 owns the whole-batch total -> running colmax for next batch
        if (g == 0) {
            gcolA[buf ^ 1][lane] = fmax4(cA[0], mA);
            gcolB[buf ^ 1][lane] = fmax4(cB[0], mB);
        }

        // elementwise merge + coalesced store
        #pragma unroll
        for (int r = 0; r < RPW; ++r) {
            const float4 oA = fmax4(cA[r], mA);
            const float4 oB = fmax4(cB[r], mB);
            float* q = oc + (size_t)(rowbase + r) * W + col;
            *(float4*)q       = make_float4(2.0f * oA.x, 2.0f * oA.y,
                                            2.0f * oA.z, 2.0f * oA.w);
            *(float4*)(q + 4) = make_float4(2.0f * oB.x, 2.0f * oB.y,
                                            2.0f * oB.z, 2.0f * oB.w);
        }

        #pragma unroll
        for (int r = 0; r < RPW; ++r) {
            cA[r] = nA[r];
            cB[r] = nB[r];
        }
        buf ^= 1;
    }
}

extern "C" void kernel_launch(void* const* d_in, const int* in_sizes, int n_in,
                              void* d_out, int out_size, void* d_ws, size_t ws_size,
                              hipStream_t stream) {
    const float* x   = (const float*)d_in[0];
    float*       out = (float*)d_out;
    tlc_kernel<<<dim3(C), dim3(512), 0, stream>>>(x, out);
}

// Round 6
// 109.509 us; speedup vs baseline: 1.0926x; 1.0926x over previous
//
#include <hip/hip_runtime.h>
#include <math.h>

// x: (C,H,W) = (256,512,512) f32.  out = 2 * suffmax_W( suffmax_H( x ) )
// suffmax_W and suffmax_H commute -> scan W first (carry-independent), merge
// the H carry elementwise after ONE barrier per batch.
constexpr int C     = 256;
constexpr int H     = 512;
constexpr int W     = 512;
constexpr int RPW   = 4;            // rows per wave per batch (VGPR-safe)
constexpr int BATCH = 8 * RPW;      // 32 rows/batch
constexpr int NB    = H / BATCH;    // 16 batches

typedef float v4f __attribute__((ext_vector_type(4)));

__device__ __forceinline__ v4f vmax4(v4f a, v4f b) {
    v4f r;
    r.x = fmaxf(a.x, b.x); r.y = fmaxf(a.y, b.y);
    r.z = fmaxf(a.z, b.z); r.w = fmaxf(a.w, b.w);
    return r;
}

// One 512-thread block per channel; lane owns 8 consecutive columns so the
// 512-col W suffix scan is one wave (7 in-lane fmax + 7 shuffles). Each wave
// owns 4 rows/batch. 16 batches fully unrolled with a 3-buffer rotation:
// while computing batch t, loads for t+1 and t+2 are in flight (no register
// copies -> no vmcnt(0) drain at batch boundaries). Nontemporal loads/stores
// (streaming, touch-once data).
__global__ __launch_bounds__(512)
void tlc_kernel(const float* __restrict__ x, float* __restrict__ out) {
    const int tid  = threadIdx.x;
    const int g    = tid >> 6;        // wave 0..7
    const int lane = tid & 63;
    const int c    = blockIdx.x;
    const int col  = lane * 8;        // first of this lane's 8 columns

    __shared__ v4f ltotA[2][8][64], ltotB[2][8][64];  // wave column totals
    __shared__ v4f gcolA[2][64],    gcolB[2][64];     // running colmax

    const float* __restrict__ xc = x   + (size_t)c * H * W;
    float*       __restrict__ oc = out + (size_t)c * H * W;

    const int s1  = min(lane + 1, 63),  s2  = min(lane + 2, 63);
    const int s4  = min(lane + 4, 63),  s8  = min(lane + 8, 63);
    const int s16 = min(lane + 16, 63), s32 = min(lane + 32, 63);

    if (g == 0) {
        const v4f ninf = (v4f){-INFINITY, -INFINITY, -INFINITY, -INFINITY};
        gcolA[0][lane] = ninf;   // ordered before first read by batch-0 barrier
        gcolB[0][lane] = ninf;
    }

    v4f b0A[RPW], b0B[RPW], b1A[RPW], b1B[RPW], b2A[RPW], b2B[RPW];

// issue batch t's loads into buffer `buf` (nontemporal, 2 b128 per row)
#define LOADB(bufA, bufB, t) {                                               \
    const float* p0 = xc + (size_t)(H - BATCH * ((t) + 1) + RPW * g) * W + col; \
    _Pragma("unroll")                                                        \
    for (int r = 0; r < RPW; ++r) {                                          \
        bufA[r] = __builtin_nontemporal_load((const v4f*)(p0 + (size_t)r * W));     \
        bufB[r] = __builtin_nontemporal_load((const v4f*)(p0 + (size_t)r * W + 4)); \
    } }

// consume buffer `buf` = batch t: W-scan in place, local H chain, publish
// totals, ONE barrier, elementwise carry merge, nontemporal store.
#define STEPC(bufA, bufB, t) {                                               \
    const int rb = H - BATCH * ((t) + 1) + RPW * g;                          \
    const int pb = (t) & 1;                                                  \
    _Pragma("unroll")                                                        \
    for (int r = 0; r < RPW; ++r) {                                          \
        const v4f a = bufA[r], b = bufB[r];                                  \
        const float t7 = b.w;                                                \
        const float t6 = fmaxf(b.z, t7);                                     \
        const float t5 = fmaxf(b.y, t6);                                     \
        const float t4 = fmaxf(b.x, t5);                                     \
        const float t3 = fmaxf(a.w, t4);                                     \
        const float t2 = fmaxf(a.z, t3);                                     \
        const float t1 = fmaxf(a.y, t2);                                     \
        const float t0 = fmaxf(a.x, t1);                                     \
        float e = __shfl(t0, s1);                                            \
        e = (lane == 63) ? -INFINITY : e;                                    \
        e = fmaxf(e, __shfl(e, s1));  e = fmaxf(e, __shfl(e, s2));           \
        e = fmaxf(e, __shfl(e, s4));  e = fmaxf(e, __shfl(e, s8));           \
        e = fmaxf(e, __shfl(e, s16)); e = fmaxf(e, __shfl(e, s32));          \
        bufA[r] = (v4f){fmaxf(t0, e), fmaxf(t1, e), fmaxf(t2, e), fmaxf(t3, e)}; \
        bufB[r] = (v4f){fmaxf(t4, e), fmaxf(t5, e), fmaxf(t6, e), fmaxf(t7, e)}; \
    }                                                                        \
    _Pragma("unroll")                                                        \
    for (int r = RPW - 2; r >= 0; --r) {                                     \
        bufA[r] = vmax4(bufA[r], bufA[r + 1]);                               \
        bufB[r] = vmax4(bufB[r], bufB[r + 1]);                               \
    }                                                                        \
    ltotA[pb][g][lane] = bufA[0];                                            \
    ltotB[pb][g][lane] = bufB[0];                                            \
    __syncthreads();                                                         \
    v4f mA = gcolA[pb][lane];                                                \
    v4f mB = gcolB[pb][lane];                                                \
    for (int gg = g + 1; gg < 8; ++gg) {                                     \
        mA = vmax4(mA, ltotA[pb][gg][lane]);                                 \
        mB = vmax4(mB, ltotB[pb][gg][lane]);                                 \
    }                                                                        \
    if (g == 0) {                                                            \
        gcolA[pb ^ 1][lane] = vmax4(bufA[0], mA);                            \
        gcolB[pb ^ 1][lane] = vmax4(bufB[0], mB);                            \
    }                                                                        \
    _Pragma("unroll")                                                        \
    for (int r = 0; r < RPW; ++r) {                                          \
        v4f oA = vmax4(bufA[r], mA) * 2.0f;                                  \
        v4f oB = vmax4(bufB[r], mB) * 2.0f;                                  \
        float* q = oc + (size_t)(rb + r) * W + col;                          \
        __builtin_nontemporal_store(oA, (v4f*)q);                            \
        __builtin_nontemporal_store(oB, (v4f*)(q + 4));                      \
    } }

    // depth-2 pipeline, 3-buffer rotation, fully unrolled (NB = 16)
    LOADB(b0A, b0B, 0)
    LOADB(b1A, b1B, 1)

    LOADB(b2A, b2B,  2)  STEPC(b0A, b0B,  0)
    LOADB(b0A, b0B,  3)  STEPC(b1A, b1B,  1)
    LOADB(b1A, b1B,  4)  STEPC(b2A, b2B,  2)
    LOADB(b2A, b2B,  5)  STEPC(b0A, b0B,  3)
    LOADB(b0A, b0B,  6)  STEPC(b1A, b1B,  4)
    LOADB(b1A, b1B,  7)  STEPC(b2A, b2B,  5)
    LOADB(b2A, b2B,  8)  STEPC(b0A, b0B,  6)
    LOADB(b0A, b0B,  9)  STEPC(b1A, b1B,  7)
    LOADB(b1A, b1B, 10)  STEPC(b2A, b2B,  8)
    LOADB(b2A, b2B, 11)  STEPC(b0A, b0B,  9)
    LOADB(b0A, b0B, 12)  STEPC(b1A, b1B, 10)
    LOADB(b1A, b1B, 13)  STEPC(b2A, b2B, 11)
    LOADB(b2A, b2B, 14)  STEPC(b0A, b0B, 12)
    LOADB(b0A, b0B, 15)  STEPC(b1A, b1B, 13)
                         STEPC(b2A, b2B, 14)
                         STEPC(b0A, b0B, 15)

#undef LOADB
#undef STEPC
}

extern "C" void kernel_launch(void* const* d_in, const int* in_sizes, int n_in,
                              void* d_out, int out_size, void* d_ws, size_t ws_size,
                              hipStream_t stream) {
    const float* x   = (const float*)d_in[0];
    float*       out = (float*)d_out;
    tlc_kernel<<<dim3(C), dim3(512), 0, stream>>>(x, out);
}